// Round 10
// baseline (187.808 us; speedup 1.0000x reference)
//
#include <hip/hip_runtime.h>
#include <math.h>

#define L 2048
#define D 1024
#define H 16
#define KS 64
#define BBATCH 2

typedef float f32x4 __attribute__((ext_vector_type(4)));
typedef short s16x8 __attribute__((ext_vector_type(8)));

__device__ __forceinline__ ushort f2bf(float f) {
    union { float f; unsigned u; } v; v.f = f;
    unsigned lsb = (v.u >> 16) & 1u;
    v.u += 0x7fffu + lsb;               // round-to-nearest-even
    return (ushort)(v.u >> 16);
}

__device__ __forceinline__ unsigned fbits(float f) {
    union { float f; unsigned u; } v; v.f = f; return v.u;
}

__device__ __forceinline__ void gl_lds16(const ushort* g, ushort* l) {
    __builtin_amdgcn_global_load_lds(
        (const __attribute__((address_space(1))) unsigned int*)g,
        (__attribute__((address_space(3))) unsigned int*)l, 16, 0, 0);
}

// ---------------------------------------------------------------------------
// Fused prep: conv_x (blocks 0..4095) | conv_w x4 (4096..8191) |
// RoPE table (8192..8447): tab[dd2*2048+s] = (cos, sin) of s*10000^(-2*dd2/64)
// ---------------------------------------------------------------------------
__global__ __launch_bounds__(256)
void prep(const float* __restrict__ x,
          const float* __restrict__ W0, const float* __restrict__ W1,
          const float* __restrict__ W2, const float* __restrict__ W3,
          ushort* __restrict__ xb, ushort* __restrict__ Wt,
          float2* __restrict__ tab)
{
    __shared__ float T[32][33];
    const int bid = blockIdx.x;
    const int tid = threadIdx.x;
    if (bid < 4096) {
        const int i = bid * 1024 + tid * 4;
        const float4 v = *(const float4*)&x[i];
        ushort4 p = make_ushort4(f2bf(v.x), f2bf(v.y), f2bf(v.z), f2bf(v.w));
        *(ushort4*)&xb[i] = p;
    } else if (bid < 8192) {
        const int t = bid - 4096;
        const int z = t >> 10;
        const float* W = (z == 0) ? W0 : (z == 1) ? W1 : (z == 2) ? W2 : W3;
        ushort* out = Wt + (size_t)z * D * D;
        const int r0 = ((t >> 5) & 31) * 32, c0 = (t & 31) * 32;
        const int tr = tid >> 3, tc = (tid & 7) * 4;
        const float4 v = *(const float4*)&W[(size_t)(r0 + tr) * D + c0 + tc];
        T[tr][tc + 0] = v.x; T[tr][tc + 1] = v.y;
        T[tr][tc + 2] = v.z; T[tr][tc + 3] = v.w;
        __syncthreads();
        ushort4 p = make_ushort4(f2bf(T[tc + 0][tr]), f2bf(T[tc + 1][tr]),
                                 f2bf(T[tc + 2][tr]), f2bf(T[tc + 3][tr]));
        *(ushort4*)&out[(size_t)(c0 + tr) * D + r0 + tc] = p;
    } else {
        const int idx = (bid - 8192) * 256 + tid;    // 0..65535
        const int dd2 = idx >> 11, s = idx & 2047;
        const float inv = __expf(-(float)(2 * dd2) * (9.210340371976184f / 64.0f));
        float sn, cs;
        sincosf((float)s * inv, &sn, &cs);
        tab[idx] = make_float2(cs, sn);
    }
}

// ---------------------------------------------------------------------------
// Fused QKV GEMM v5 — 192x256 tile, BK=32, 8 waves (2M x 4N), 256 blocks.
// NEW: ring-2 double buffer (2 x 28KB = 56KB LDS) -> 2 BLOCKS/CU (was 1 at
// ring-4/112KB). Distance-1 gl_lds prefetch, vmcnt(0) at each K-boundary —
// the drain stall is covered by the co-resident block (m97/m114 mechanism:
// 874 TF came from ~3 blocks/CU + plain dbuf, not from deeper rings).
// Wave-role staging (waves 0-3: A, 3 loads; 4-7: B, 4 loads), both-sides
// XOR swizzle, compiler-scheduled lgkmcnt (no manual pins).
// ---------------------------------------------------------------------------
__global__ __launch_bounds__(512, 2)
void qkv_gemm(const ushort* __restrict__ A, const ushort* __restrict__ B,
              const float2* __restrict__ tab,
              ushort* __restrict__ Qo, ushort* __restrict__ Ko,
              ushort* __restrict__ Vto)
{
    __shared__ __align__(16) ushort smem[28672];   // 56 KiB: 2 x (A 6144 + B 8192) ushorts
    const int tid  = threadIdx.x;
    const int wv   = tid >> 6, lane = tid & 63;
    const int i16  = lane & 15, quad = lane >> 4;
    const int wr   = wv >> 2, wc = wv & 3;         // 2M x 4N waves

    // XCD-aware bijective swizzle (256 blocks, 256 % 8 == 0)
    int bid = blockIdx.y * 16 + blockIdx.x;
    bid = (bid & 7) * 32 + (bid >> 3);
    const int by = bid & 15, bx = bid >> 4;
    const int m0 = by * 192, n0 = bx * 256;

    // wave-role staging: waves 0-3 -> A (768 chunks), waves 4-7 -> B (1024)
    const bool isAw = (wv < 4);
    const int cb = isAw ? tid : (tid - 256);
    const ushort* Mp = isAw ? A : B;
    const int rbase = isAw ? m0 : n0;
    const int lbo   = isAw ? 0 : 6144;
    const int c0 = cb, c1 = 256 + cb, c2 = 512 + cb, c3 = 768 + cb;
    const size_t src0 = (size_t)(rbase + (c0 >> 2)) * D + (((c0 & 3) * 8) ^ (((c0 >> 4) & 3) << 3));
    const size_t src1 = (size_t)(rbase + (c1 >> 2)) * D + (((c1 & 3) * 8) ^ (((c1 >> 4) & 3) << 3));
    const size_t src2 = (size_t)(rbase + (c2 >> 2)) * D + (((c2 & 3) * 8) ^ (((c2 >> 4) & 3) << 3));
    const size_t src3 = (size_t)(rbase + (c3 >> 2)) * D + (((c3 & 3) * 8) ^ (((c3 >> 4) & 3) << 3));
    const int ldo0 = lbo + c0 * 8, ldo1 = lbo + c1 * 8;
    const int ldo2 = lbo + c2 * 8, ldo3 = lbo + c3 * 8;

    f32x4 acc[6][4];
    #pragma unroll
    for (int i = 0; i < 6; ++i)
        #pragma unroll
        for (int j = 0; j < 4; ++j) acc[i][j] = (f32x4){0.f, 0.f, 0.f, 0.f};

#define STAGE(kt) do { ushort* S_ = smem + ((kt) & 1) * 14336;                \
        gl_lds16(Mp + src0 + (size_t)(kt) * 32, S_ + ldo0);                   \
        gl_lds16(Mp + src1 + (size_t)(kt) * 32, S_ + ldo1);                   \
        gl_lds16(Mp + src2 + (size_t)(kt) * 32, S_ + ldo2);                   \
        if (!isAw) gl_lds16(Mp + src3 + (size_t)(kt) * 32, S_ + ldo3); } while (0)

    // Prologue: stage tile 0 into slot 0, drain, barrier.
    STAGE(0);
    asm volatile("s_waitcnt vmcnt(0)" ::: "memory");
    __builtin_amdgcn_s_barrier();
    __builtin_amdgcn_sched_barrier(0);

    #pragma unroll 1
    for (int kt = 0; kt < 32; ++kt) {
        const ushort* As = smem + (kt & 1) * 14336;
        const ushort* Bs = As + 6144;
        s16x8 afr[6], bfr[4];

        #pragma unroll
        for (int mf = 0; mf < 6; ++mf) {
            int ad = (wr * 96 + mf * 16 + i16) * 64 + quad * 16;
            ad ^= ((ad >> 8) & 3) << 4;
            afr[mf] = *(const s16x8*)((const char*)As + ad);
        }
        #pragma unroll
        for (int nf = 0; nf < 4; ++nf) {
            int ad = (wc * 64 + nf * 16 + i16) * 64 + quad * 16;
            ad ^= ((ad >> 8) & 3) << 4;
            bfr[nf] = *(const s16x8*)((const char*)Bs + ad);
        }
        if (kt < 31) STAGE(kt + 1);          // distance-1 into the other slot
        // compiler interleaves ds_reads with MFMAs via counted lgkmcnt
        #pragma unroll
        for (int mf = 0; mf < 6; ++mf)
            #pragma unroll
            for (int nf = 0; nf < 4; ++nf)
                acc[mf][nf] = __builtin_amdgcn_mfma_f32_16x16x32_bf16(
                    afr[mf], bfr[nf], acc[mf][nf], 0, 0, 0);

        // boundary: this-iter staging landed for every thread, then flip
        asm volatile("s_waitcnt vmcnt(0)" ::: "memory");
        __builtin_amdgcn_s_barrier();
        __builtin_amdgcn_sched_barrier(0);   // keep next-iter reads below barrier
    }
#undef STAGE

    // ---- per-fragment epilogue (fragments are region-pure: 1024 % 16 == 0) ----
    const int tbase = n0 + wc * 64;
    ushort* T = smem + wv * 1152;            // wave-local [16][72]
    #pragma unroll
    for (int mf = 0; mf < 6; ++mf) {
        const int dim0 = m0 + wr * 96 + mf * 16;
        const int region = dim0 >> 10;       // 0=Q, 1=K, 2=V
        if (region < 2) {
            ushort* out = (region == 0) ? Qo : Ko;
            const bool isQ = (region == 0);
            const int qd = (dim0 & 1023) + quad * 4;
            const int hh = qd >> 6, dd = qd & 63;
            #pragma unroll
            for (int nf = 0; nf < 4; ++nf) {
                const int token = tbase + nf * 16 + i16;
                const int b = token >> 11, s = token & 2047;
                ushort4 p;
                #pragma unroll
                for (int pr = 0; pr < 2; ++pr) {
                    float e = acc[mf][nf][2 * pr];
                    float o = acc[mf][nf][2 * pr + 1];
                    if (isQ) { e *= 0.03125f; o *= 0.03125f; }
                    const float2 cssn = tab[(size_t)((dd >> 1) + pr) * 2048 + s];
                    const float ne = e * cssn.x - o * cssn.y;
                    const float no = o * cssn.x + e * cssn.y;
                    if (pr == 0) { p.x = f2bf(ne); p.y = f2bf(no); }
                    else         { p.z = f2bf(ne); p.w = f2bf(no); }
                }
                *(ushort4*)&out[((size_t)(b * H + hh) * L + s) * KS + dd] = p;
            }
        } else {
            // V fragment: wave-local 16x64 LDS transpose -> coalesced Vt store
            #pragma unroll
            for (int nf = 0; nf < 4; ++nf)
                #pragma unroll
                for (int r = 0; r < 4; ++r)
                    T[(quad * 4 + r) * 72 + nf * 16 + i16] = f2bf(acc[mf][nf][r]);
            __builtin_amdgcn_s_waitcnt(0);   // wave-local LDS drain
            const int tl0 = (lane & 7) * 8;
            #pragma unroll
            for (int c = 0; c < 2; ++c) {
                const int vl = c * 8 + (lane >> 3);
                const s16x8 val = *(const s16x8*)&T[vl * 72 + tl0];
                const int vdim = (dim0 - 2048) + vl;
                const int hh = vdim >> 6, dd = vdim & 63;
                const int token0 = tbase + tl0;
                const int b = token0 >> 11, s0 = token0 & 2047;
                *(s16x8*)&Vto[((size_t)(b * H + hh) * KS + dd) * L + s0] = val;
            }
            __builtin_amdgcn_s_waitcnt(0);   // reads done before next frag reuses T
        }
    }
}

// ---------------------------------------------------------------------------
// O-projection GEMM v3 — 128x128 tile, BK=32, 8 waves (2M x 4N, wave tile
// 64x32), 512 threads, ring-4 LDS 64KB (2 blocks/CU), 1 gl_lds16/thread/
// operand/kt, single barrier per K-step, counted vmcnt 4/2/0. Unchanged.
// ---------------------------------------------------------------------------
__global__ __launch_bounds__(512)
void oproj_gemm(const ushort* __restrict__ A, const ushort* __restrict__ B,
                float* __restrict__ out)
{
    __shared__ __align__(16) ushort smem[32768];   // 64 KiB: 4 x (A 4096 + B 4096)
    const int tid  = threadIdx.x;
    const int wv   = tid >> 6, lane = tid & 63;
    const int i16  = lane & 15, quad = lane >> 4;
    const int wr   = wv >> 2, wc = wv & 3;         // 2M x 4N waves

    const int bid = blockIdx.y * 8 + blockIdx.x;
    const int bx  = bid & 7, by = bid >> 3;
    const int m0  = by * 128, n0 = bx * 128;

    // staging: 512 x 16B chunks per operand tile, 1/thread/operand
    const int c = tid;
    const size_t sA = (size_t)(m0 + (c >> 2)) * D + (((c & 3) * 8) ^ (((c >> 4) & 3) << 3));
    const size_t sB = (size_t)(n0 + (c >> 2)) * D + (((c & 3) * 8) ^ (((c >> 4) & 3) << 3));
    const int ldo = c * 8;

    f32x4 acc[4][2];
    #pragma unroll
    for (int i = 0; i < 4; ++i)
        #pragma unroll
        for (int j = 0; j < 2; ++j) acc[i][j] = (f32x4){0.f, 0.f, 0.f, 0.f};

#define OSTAGE(kt) do { ushort* S_ = smem + ((kt) & 3) * 8192;                \
        gl_lds16(A + sA + (size_t)(kt) * 32, S_ + ldo);                       \
        gl_lds16(B + sB + (size_t)(kt) * 32, S_ + 4096 + ldo); } while (0)

    OSTAGE(0); OSTAGE(1); OSTAGE(2);               // 6 loads/thread
    asm volatile("s_waitcnt vmcnt(4)" ::: "memory");
    __builtin_amdgcn_s_barrier();
    __builtin_amdgcn_sched_barrier(0);

    #pragma unroll 1
    for (int kt = 0; kt < 32; ++kt) {
        const ushort* As = smem + (kt & 3) * 8192;
        const ushort* Bs = As + 4096;
        s16x8 afr[4], bfr[2];
        #pragma unroll
        for (int mf = 0; mf < 4; ++mf) {
            int ad = (wr * 64 + mf * 16 + i16) * 64 + quad * 16;
            ad ^= ((ad >> 8) & 3) << 4;
            afr[mf] = *(const s16x8*)((const char*)As + ad);
        }
        #pragma unroll
        for (int nf = 0; nf < 2; ++nf) {
            int ad = (wc * 32 + nf * 16 + i16) * 64 + quad * 16;
            ad ^= ((ad >> 8) & 3) << 4;
            bfr[nf] = *(const s16x8*)((const char*)Bs + ad);
        }
        if (kt < 29) OSTAGE(kt + 3);
        #pragma unroll
        for (int mf = 0; mf < 4; ++mf)
            #pragma unroll
            for (int nf = 0; nf < 2; ++nf)
                acc[mf][nf] = __builtin_amdgcn_mfma_f32_16x16x32_bf16(
                    afr[mf], bfr[nf], acc[mf][nf], 0, 0, 0);

        if (kt <= 28)      { asm volatile("s_waitcnt vmcnt(4)" ::: "memory"); }
        else if (kt == 29) { asm volatile("s_waitcnt vmcnt(2)" ::: "memory"); }
        else if (kt == 30) { asm volatile("s_waitcnt vmcnt(0)" ::: "memory"); }
        __builtin_amdgcn_s_barrier();
        __builtin_amdgcn_sched_barrier(0);
    }
#undef OSTAGE

    #pragma unroll
    for (int mf = 0; mf < 4; ++mf)
        #pragma unroll
        for (int nf = 0; nf < 2; ++nf) {
            const int od = n0 + wc * 32 + nf * 16 + i16;
            const int tk = m0 + wr * 64 + mf * 16 + quad * 4;
            #pragma unroll
            for (int r = 0; r < 4; ++r)
                out[(size_t)(tk + r) * D + od] = acc[mf][nf][r];
        }
}

// ---------------------------------------------------------------------------
// MFMA flash attention v5: 8 waves x 16 q-rows, 512 threads, grid 16x32,
// qt-pairing load balance, linear [64][64] K/V LDS + both-sides XOR swizzle,
// gl_lds staging depth-2 ring. Verified round 6. Unchanged.
// ---------------------------------------------------------------------------
__global__ __launch_bounds__(512)
void attn_mfma(const ushort* __restrict__ Q, const ushort* __restrict__ K,
               const ushort* __restrict__ Vt, ushort* __restrict__ Yb)
{
    const int bh   = blockIdx.y;
    const int qt   = (bh < 16) ? (15 - blockIdx.x) : blockIdx.x;
    const int tid  = threadIdx.x;
    const int wave = tid >> 6, lane = tid & 63;
    const int i16  = lane & 15, quad = lane >> 4;
    const int r0   = qt * 128 + wave * 16;
    const int row  = r0 + i16;
    const int jtmax = (r0 + 15) >> 6;        // this wave's diagonal k-tile
    const int jtend = 2 * qt + 1;            // block's last k-tile

    __shared__ __align__(16) ushort Ks[2][64 * 64];
    __shared__ __align__(16) ushort Vs[2][64 * 64];
    __shared__ __align__(16) ushort Ps[8][16 * 72];

    const ushort* Qb = Q  + (size_t)bh * L * KS;
    const ushort* Kb = K  + (size_t)bh * L * KS;
    const ushort* Vb = Vt + (size_t)bh * KS * L;

    const s16x8 qf0 = *(const s16x8*)(Qb + (size_t)row * KS + quad * 8);
    const s16x8 qf1 = *(const s16x8*)(Qb + (size_t)row * KS + 32 + quad * 8);

    const int srow = tid >> 3;                               // 0..63
    const int scol = ((tid & 7) ^ ((tid >> 3) & 7)) * 8;     // ushorts
    ushort* kd0 = &Ks[0][0] + tid * 8;
    ushort* vd0 = &Vs[0][0] + tid * 8;
    ushort* kd1 = &Ks[1][0] + tid * 8;
    ushort* vd1 = &Vs[1][0] + tid * 8;

    gl_lds16(Kb + (size_t)srow * KS + scol, kd0);
    gl_lds16(Vb + (size_t)srow * L + scol, vd0);
    asm volatile("s_waitcnt vmcnt(0)" ::: "memory");
    __builtin_amdgcn_s_barrier();

    f32x4 O0 = {0.f,0.f,0.f,0.f}, O1 = O0, O2 = O0, O3 = O0;
    float psum = 0.0f;
    const int xk = (i16 & 7) << 4;           // read swizzle key (row = nt*16+i16)

    #pragma unroll 1
    for (int jt = 0; jt <= jtend; ++jt) {
        const int cur = jt & 1;
        const bool has_next = (jt < jtend);

        if (has_next) {
            const int j0n = (jt + 1) * 64;
            gl_lds16(Kb + (size_t)(j0n + srow) * KS + scol, cur ? kd0 : kd1);
            gl_lds16(Vb + (size_t)srow * L + j0n + scol,    cur ? vd0 : vd1);
        }

        if (jt <= jtmax) {
            const int j0 = jt * 64;
            const char* Ksb = (const char*)&Ks[cur][0];
            const char* Vsb = (const char*)&Vs[cur][0];
            f32x4 st[4];
            #pragma unroll
            for (int nt = 0; nt < 4; ++nt) {
                const int rb = (nt * 16 + i16) * 128 + quad * 16;
                const s16x8 kf0 = *(const s16x8*)(Ksb + (rb ^ xk));
                const s16x8 kf1 = *(const s16x8*)(Ksb + ((rb + 64) ^ xk));
                f32x4 c = {0.f,0.f,0.f,0.f};
                c = __builtin_amdgcn_mfma_f32_16x16x32_bf16(kf0, qf0, c, 0, 0, 0);
                c = __builtin_amdgcn_mfma_f32_16x16x32_bf16(kf1, qf1, c, 0, 0, 0);
                st[nt] = c;
            }
            if (jt == jtmax) {
                #pragma unroll
                for (int nt = 0; nt < 4; ++nt)
                    #pragma unroll
                    for (int rg = 0; rg < 4; ++rg) {
                        const int j = j0 + nt * 16 + quad * 4 + rg;
                        if (j > row) st[nt][rg] = -1e30f;
                    }
            }
            float pv[4][4];
            #pragma unroll
            for (int nt = 0; nt < 4; ++nt)
                #pragma unroll
                for (int rg = 0; rg < 4; ++rg) {
                    pv[nt][rg] = __expf(st[nt][rg]);
                    psum += pv[nt][rg];
                }
            ushort* P2 = &Ps[wave][0];
            #pragma unroll
            for (int nt = 0; nt < 4; ++nt) {
                uint2 pk;
                pk.x = __builtin_amdgcn_perm(fbits(pv[nt][1]), fbits(pv[nt][0]), 0x07060302u);
                pk.y = __builtin_amdgcn_perm(fbits(pv[nt][3]), fbits(pv[nt][2]), 0x07060302u);
                *(uint2*)(P2 + i16 * 72 + nt * 16 + quad * 4) = pk;
            }
            const s16x8 pf0 = *(const s16x8*)(P2 + i16 * 72 + quad * 8);
            const s16x8 pf1 = *(const s16x8*)(P2 + i16 * 72 + 32 + quad * 8);
            s16x8 v0, v1;
            int vb0 = (0 * 16 + i16) * 128 + quad * 16;
            v0 = *(const s16x8*)(Vsb + (vb0 ^ xk));
            v1 = *(const s16x8*)(Vsb + ((vb0 + 64) ^ xk));
            O0 = __builtin_amdgcn_mfma_f32_16x16x32_bf16(v0, pf0, O0, 0, 0, 0);
            O0 = __builtin_amdgcn_mfma_f32_16x16x32_bf16(v1, pf1, O0, 0, 0, 0);
            vb0 = (1 * 16 + i16) * 128 + quad * 16;
            v0 = *(const s16x8*)(Vsb + (vb0 ^ xk));
            v1 = *(const s16x8*)(Vsb + ((vb0 + 64) ^ xk));
            O1 = __builtin_amdgcn_mfma_f32_16x16x32_bf16(v0, pf0, O1, 0, 0, 0);
            O1 = __builtin_amdgcn_mfma_f32_16x16x32_bf16(v1, pf1, O1, 0, 0, 0);
            vb0 = (2 * 16 + i16) * 128 + quad * 16;
            v0 = *(const s16x8*)(Vsb + (vb0 ^ xk));
            v1 = *(const s16x8*)(Vsb + ((vb0 + 64) ^ xk));
            O2 = __builtin_amdgcn_mfma_f32_16x16x32_bf16(v0, pf0, O2, 0, 0, 0);
            O2 = __builtin_amdgcn_mfma_f32_16x16x32_bf16(v1, pf1, O2, 0, 0, 0);
            vb0 = (3 * 16 + i16) * 128 + quad * 16;
            v0 = *(const s16x8*)(Vsb + (vb0 ^ xk));
            v1 = *(const s16x8*)(Vsb + ((vb0 + 64) ^ xk));
            O3 = __builtin_amdgcn_mfma_f32_16x16x32_bf16(v0, pf0, O3, 0, 0, 0);
            O3 = __builtin_amdgcn_mfma_f32_16x16x32_bf16(v1, pf1, O3, 0, 0, 0);
        }

        if (has_next) {
            asm volatile("s_waitcnt vmcnt(0)" ::: "memory");
            __builtin_amdgcn_s_barrier();
        }
    }

    psum += __shfl_xor(psum, 16);
    psum += __shfl_xor(psum, 32);
    const float inv_l = __builtin_amdgcn_rcpf(psum);
    const int b = bh >> 4, hh = bh & 15;
    ushort* Yp = Yb + ((size_t)(b * L + row)) * D + hh * KS + quad * 4;
    f32x4 r;
    r = O0 * inv_l; *(ushort4*)(Yp +  0) = make_ushort4(f2bf(r[0]),f2bf(r[1]),f2bf(r[2]),f2bf(r[3]));
    r = O1 * inv_l; *(ushort4*)(Yp + 16) = make_ushort4(f2bf(r[0]),f2bf(r[1]),f2bf(r[2]),f2bf(r[3]));
    r = O2 * inv_l; *(ushort4*)(Yp + 32) = make_ushort4(f2bf(r[0]),f2bf(r[1]),f2bf(r[2]),f2bf(r[3]));
    r = O3 * inv_l; *(ushort4*)(Yp + 48) = make_ushort4(f2bf(r[0]),f2bf(r[1]),f2bf(r[2]),f2bf(r[3]));
}

// ---------------------------------------------------------------------------
extern "C" void kernel_launch(void* const* d_in, const int* in_sizes, int n_in,
                              void* d_out, int out_size, void* d_ws, size_t ws_size,
                              hipStream_t stream)
{
    const float* x  = (const float*)d_in[0];
    // d_in[1] = mask (unused; causal handled analytically)
    const float* Wq = (const float*)d_in[2];
    const float* Wk = (const float*)d_in[3];
    const float* Wv = (const float*)d_in[4];
    const float* Wo = (const float*)d_in[5];

    const size_t NTOK = (size_t)BBATCH * L;         // 4096
    const size_t SZ   = NTOK * D;                   // 4 M elems
    ushort* xb  = (ushort*)d_ws;                    // [4096][1024]
    ushort* Wt  = xb + SZ;                          // [Wq^T;Wk^T;Wv^T;Wo^T]
    ushort* Qb  = Wt + 4 * (size_t)D * D;           // [bh][l][64]
    ushort* Kb  = Qb + SZ;
    ushort* Vtb = Kb + SZ;                          // [bh][64][l]
    ushort* Yb  = Vtb + SZ;                         // [4096][1024]
    float2* tab = (float2*)Yb;                      // aliases Yb: consumed by
                                                    // qkv before attn writes Yb

    prep<<<dim3(8448), dim3(256), 0, stream>>>(x, Wq, Wk, Wv, Wo, xb, Wt, tab);

    qkv_gemm<<<dim3(16, 16), dim3(512), 0, stream>>>(Wt, xb, tab, Qb, Kb, Vtb);

    attn_mfma<<<dim3(16, 32), dim3(512), 0, stream>>>(Qb, Kb, Vtb, Yb);

    oproj_gemm<<<dim3(8, 32), dim3(512), 0, stream>>>(Yb, Wt + 3 * (size_t)D * D,
                                                      (float*)d_out);
}

// Round 11
// 176.956 us; speedup vs baseline: 1.0613x; 1.0613x over previous
//
#include <hip/hip_runtime.h>
#include <math.h>

#define L 2048
#define D 1024
#define H 16
#define KS 64
#define BBATCH 2

typedef float f32x4 __attribute__((ext_vector_type(4)));
typedef short s16x8 __attribute__((ext_vector_type(8)));

__device__ __forceinline__ ushort f2bf(float f) {
    union { float f; unsigned u; } v; v.f = f;
    unsigned lsb = (v.u >> 16) & 1u;
    v.u += 0x7fffu + lsb;               // round-to-nearest-even
    return (ushort)(v.u >> 16);
}

__device__ __forceinline__ unsigned fbits(float f) {
    union { float f; unsigned u; } v; v.f = f; return v.u;
}

__device__ __forceinline__ void gl_lds16(const ushort* g, ushort* l) {
    __builtin_amdgcn_global_load_lds(
        (const __attribute__((address_space(1))) unsigned int*)g,
        (__attribute__((address_space(3))) unsigned int*)l, 16, 0, 0);
}

// ---------------------------------------------------------------------------
// Fused prep: conv_x (blocks 0..4095) | conv_w x4 (4096..8191) |
// RoPE table (8192..8447): tab[dd2*2048+s] = (cos, sin) of s*10000^(-2*dd2/64)
// ---------------------------------------------------------------------------
__global__ __launch_bounds__(256)
void prep(const float* __restrict__ x,
          const float* __restrict__ W0, const float* __restrict__ W1,
          const float* __restrict__ W2, const float* __restrict__ W3,
          ushort* __restrict__ xb, ushort* __restrict__ Wt,
          float2* __restrict__ tab)
{
    __shared__ float T[32][33];
    const int bid = blockIdx.x;
    const int tid = threadIdx.x;
    if (bid < 4096) {
        const int i = bid * 1024 + tid * 4;
        const float4 v = *(const float4*)&x[i];
        ushort4 p = make_ushort4(f2bf(v.x), f2bf(v.y), f2bf(v.z), f2bf(v.w));
        *(ushort4*)&xb[i] = p;
    } else if (bid < 8192) {
        const int t = bid - 4096;
        const int z = t >> 10;
        const float* W = (z == 0) ? W0 : (z == 1) ? W1 : (z == 2) ? W2 : W3;
        ushort* out = Wt + (size_t)z * D * D;
        const int r0 = ((t >> 5) & 31) * 32, c0 = (t & 31) * 32;
        const int tr = tid >> 3, tc = (tid & 7) * 4;
        const float4 v = *(const float4*)&W[(size_t)(r0 + tr) * D + c0 + tc];
        T[tr][tc + 0] = v.x; T[tr][tc + 1] = v.y;
        T[tr][tc + 2] = v.z; T[tr][tc + 3] = v.w;
        __syncthreads();
        ushort4 p = make_ushort4(f2bf(T[tc + 0][tr]), f2bf(T[tc + 1][tr]),
                                 f2bf(T[tc + 2][tr]), f2bf(T[tc + 3][tr]));
        *(ushort4*)&out[(size_t)(c0 + tr) * D + r0 + tc] = p;
    } else {
        const int idx = (bid - 8192) * 256 + tid;    // 0..65535
        const int dd2 = idx >> 11, s = idx & 2047;
        const float inv = __expf(-(float)(2 * dd2) * (9.210340371976184f / 64.0f));
        float sn, cs;
        sincosf((float)s * inv, &sn, &cs);
        tab[idx] = make_float2(cs, sn);
    }
}

// ---------------------------------------------------------------------------
// Fused QKV GEMM v4 — 192x256 tile, BK=32, 8 waves (2M x 4N), 256 blocks,
// ring-4 LDS (112KB), distance-3 gl_lds prefetch, counted per-role vmcnt,
// both-sides XOR swizzle, compiler-scheduled lgkmcnt (no manual pins).
// Best measured config (round 9: total 178.1 us).
// ---------------------------------------------------------------------------
__global__ __launch_bounds__(512, 2)
void qkv_gemm(const ushort* __restrict__ A, const ushort* __restrict__ B,
              const float2* __restrict__ tab,
              ushort* __restrict__ Qo, ushort* __restrict__ Ko,
              ushort* __restrict__ Vto)
{
    __shared__ __align__(16) ushort smem[57344];   // 112 KiB: 4 x (A 6144 + B 8192) ushorts
    const int tid  = threadIdx.x;
    const int wv   = tid >> 6, lane = tid & 63;
    const int i16  = lane & 15, quad = lane >> 4;
    const int wr   = wv >> 2, wc = wv & 3;         // 2M x 4N waves

    // XCD-aware bijective swizzle (256 blocks, 256 % 8 == 0)
    int bid = blockIdx.y * 16 + blockIdx.x;
    bid = (bid & 7) * 32 + (bid >> 3);
    const int by = bid & 15, bx = bid >> 4;
    const int m0 = by * 192, n0 = bx * 256;

    // wave-role staging: waves 0-3 -> A (768 chunks), waves 4-7 -> B (1024)
    const bool isAw = (wv < 4);
    const int cb = isAw ? tid : (tid - 256);
    const ushort* Mp = isAw ? A : B;
    const int rbase = isAw ? m0 : n0;
    const int lbo   = isAw ? 0 : 6144;
    const int c0 = cb, c1 = 256 + cb, c2 = 512 + cb, c3 = 768 + cb;
    const size_t src0 = (size_t)(rbase + (c0 >> 2)) * D + (((c0 & 3) * 8) ^ (((c0 >> 4) & 3) << 3));
    const size_t src1 = (size_t)(rbase + (c1 >> 2)) * D + (((c1 & 3) * 8) ^ (((c1 >> 4) & 3) << 3));
    const size_t src2 = (size_t)(rbase + (c2 >> 2)) * D + (((c2 & 3) * 8) ^ (((c2 >> 4) & 3) << 3));
    const size_t src3 = (size_t)(rbase + (c3 >> 2)) * D + (((c3 & 3) * 8) ^ (((c3 >> 4) & 3) << 3));
    const int ldo0 = lbo + c0 * 8, ldo1 = lbo + c1 * 8;
    const int ldo2 = lbo + c2 * 8, ldo3 = lbo + c3 * 8;

    f32x4 acc[6][4];
    #pragma unroll
    for (int i = 0; i < 6; ++i)
        #pragma unroll
        for (int j = 0; j < 4; ++j) acc[i][j] = (f32x4){0.f, 0.f, 0.f, 0.f};

#define STAGE(kt) do { ushort* S_ = smem + ((kt) & 3) * 14336;                \
        gl_lds16(Mp + src0 + (size_t)(kt) * 32, S_ + ldo0);                   \
        gl_lds16(Mp + src1 + (size_t)(kt) * 32, S_ + ldo1);                   \
        gl_lds16(Mp + src2 + (size_t)(kt) * 32, S_ + ldo2);                   \
        if (!isAw) gl_lds16(Mp + src3 + (size_t)(kt) * 32, S_ + ldo3); } while (0)

    // Prologue: stage tiles 0,1,2; wait until tile 0 landed (leave 1,2 in flight).
    STAGE(0); STAGE(1); STAGE(2);
    if (isAw) { asm volatile("s_waitcnt vmcnt(6)" ::: "memory"); }
    else      { asm volatile("s_waitcnt vmcnt(8)" ::: "memory"); }
    __builtin_amdgcn_s_barrier();
    __builtin_amdgcn_sched_barrier(0);

    #pragma unroll 1
    for (int kt = 0; kt < 32; ++kt) {
        const ushort* As = smem + (kt & 3) * 14336;
        const ushort* Bs = As + 6144;
        s16x8 afr[6], bfr[4];

        #pragma unroll
        for (int mf = 0; mf < 6; ++mf) {
            int ad = (wr * 96 + mf * 16 + i16) * 64 + quad * 16;
            ad ^= ((ad >> 8) & 3) << 4;
            afr[mf] = *(const s16x8*)((const char*)As + ad);
        }
        #pragma unroll
        for (int nf = 0; nf < 4; ++nf) {
            int ad = (wc * 64 + nf * 16 + i16) * 64 + quad * 16;
            ad ^= ((ad >> 8) & 3) << 4;
            bfr[nf] = *(const s16x8*)((const char*)Bs + ad);
        }
        if (kt < 29) STAGE(kt + 3);
        // no manual lgkmcnt/sched_barrier: compiler interleaves reads & MFMAs
        #pragma unroll
        for (int mf = 0; mf < 6; ++mf)
            #pragma unroll
            for (int nf = 0; nf < 4; ++nf)
                acc[mf][nf] = __builtin_amdgcn_mfma_f32_16x16x32_bf16(
                    afr[mf], bfr[nf], acc[mf][nf], 0, 0, 0);

        // K-tile boundary: tile kt+1 must be landed; tiles kt+2/kt+3 in flight.
        if (kt <= 28) {
            if (isAw) { asm volatile("s_waitcnt vmcnt(6)" ::: "memory"); }
            else      { asm volatile("s_waitcnt vmcnt(8)" ::: "memory"); }
        } else if (kt == 29) {
            if (isAw) { asm volatile("s_waitcnt vmcnt(3)" ::: "memory"); }
            else      { asm volatile("s_waitcnt vmcnt(4)" ::: "memory"); }
        } else if (kt == 30) {
            asm volatile("s_waitcnt vmcnt(0)" ::: "memory");
        }
        __builtin_amdgcn_s_barrier();
        __builtin_amdgcn_sched_barrier(0);   // keep next-iter reads below barrier
    }
#undef STAGE

    // ---- per-fragment epilogue (fragments are region-pure: 1024 % 16 == 0) ----
    const int tbase = n0 + wc * 64;
    ushort* T = smem + wv * 1152;            // wave-local [16][72]
    #pragma unroll
    for (int mf = 0; mf < 6; ++mf) {
        const int dim0 = m0 + wr * 96 + mf * 16;
        const int region = dim0 >> 10;       // 0=Q, 1=K, 2=V
        if (region < 2) {
            ushort* out = (region == 0) ? Qo : Ko;
            const bool isQ = (region == 0);
            const int qd = (dim0 & 1023) + quad * 4;
            const int hh = qd >> 6, dd = qd & 63;
            #pragma unroll
            for (int nf = 0; nf < 4; ++nf) {
                const int token = tbase + nf * 16 + i16;
                const int b = token >> 11, s = token & 2047;
                ushort4 p;
                #pragma unroll
                for (int pr = 0; pr < 2; ++pr) {
                    float e = acc[mf][nf][2 * pr];
                    float o = acc[mf][nf][2 * pr + 1];
                    if (isQ) { e *= 0.03125f; o *= 0.03125f; }
                    const float2 cssn = tab[(size_t)((dd >> 1) + pr) * 2048 + s];
                    const float ne = e * cssn.x - o * cssn.y;
                    const float no = o * cssn.x + e * cssn.y;
                    if (pr == 0) { p.x = f2bf(ne); p.y = f2bf(no); }
                    else         { p.z = f2bf(ne); p.w = f2bf(no); }
                }
                *(ushort4*)&out[((size_t)(b * H + hh) * L + s) * KS + dd] = p;
            }
        } else {
            // V fragment: wave-local 16x64 LDS transpose -> coalesced Vt store
            #pragma unroll
            for (int nf = 0; nf < 4; ++nf)
                #pragma unroll
                for (int r = 0; r < 4; ++r)
                    T[(quad * 4 + r) * 72 + nf * 16 + i16] = f2bf(acc[mf][nf][r]);
            __builtin_amdgcn_s_waitcnt(0);   // wave-local LDS drain
            const int tl0 = (lane & 7) * 8;
            #pragma unroll
            for (int c = 0; c < 2; ++c) {
                const int vl = c * 8 + (lane >> 3);
                const s16x8 val = *(const s16x8*)&T[vl * 72 + tl0];
                const int vdim = (dim0 - 2048) + vl;
                const int hh = vdim >> 6, dd = vdim & 63;
                const int token0 = tbase + tl0;
                const int b = token0 >> 11, s0 = token0 & 2047;
                *(s16x8*)&Vto[((size_t)(b * H + hh) * KS + dd) * L + s0] = val;
            }
            __builtin_amdgcn_s_waitcnt(0);   // reads done before next frag reuses T
        }
    }
}

// ---------------------------------------------------------------------------
// O-projection GEMM v3 — 128x128 tile, BK=32, 8 waves (2M x 4N, wave tile
// 64x32), 512 threads, ring-4 LDS 64KB (2 blocks/CU), 1 gl_lds16/thread/
// operand/kt, single barrier per K-step, counted vmcnt 4/2/0. Unchanged.
// ---------------------------------------------------------------------------
__global__ __launch_bounds__(512)
void oproj_gemm(const ushort* __restrict__ A, const ushort* __restrict__ B,
                float* __restrict__ out)
{
    __shared__ __align__(16) ushort smem[32768];   // 64 KiB: 4 x (A 4096 + B 4096)
    const int tid  = threadIdx.x;
    const int wv   = tid >> 6, lane = tid & 63;
    const int i16  = lane & 15, quad = lane >> 4;
    const int wr   = wv >> 2, wc = wv & 3;         // 2M x 4N waves

    const int bid = blockIdx.y * 8 + blockIdx.x;
    const int bx  = bid & 7, by = bid >> 3;
    const int m0  = by * 128, n0 = bx * 128;

    // staging: 512 x 16B chunks per operand tile, 1/thread/operand
    const int c = tid;
    const size_t sA = (size_t)(m0 + (c >> 2)) * D + (((c & 3) * 8) ^ (((c >> 4) & 3) << 3));
    const size_t sB = (size_t)(n0 + (c >> 2)) * D + (((c & 3) * 8) ^ (((c >> 4) & 3) << 3));
    const int ldo = c * 8;

    f32x4 acc[4][2];
    #pragma unroll
    for (int i = 0; i < 4; ++i)
        #pragma unroll
        for (int j = 0; j < 2; ++j) acc[i][j] = (f32x4){0.f, 0.f, 0.f, 0.f};

#define OSTAGE(kt) do { ushort* S_ = smem + ((kt) & 3) * 8192;                \
        gl_lds16(A + sA + (size_t)(kt) * 32, S_ + ldo);                       \
        gl_lds16(B + sB + (size_t)(kt) * 32, S_ + 4096 + ldo); } while (0)

    OSTAGE(0); OSTAGE(1); OSTAGE(2);               // 6 loads/thread
    asm volatile("s_waitcnt vmcnt(4)" ::: "memory");
    __builtin_amdgcn_s_barrier();
    __builtin_amdgcn_sched_barrier(0);

    #pragma unroll 1
    for (int kt = 0; kt < 32; ++kt) {
        const ushort* As = smem + (kt & 3) * 8192;
        const ushort* Bs = As + 4096;
        s16x8 afr[4], bfr[2];
        #pragma unroll
        for (int mf = 0; mf < 4; ++mf) {
            int ad = (wr * 64 + mf * 16 + i16) * 64 + quad * 16;
            ad ^= ((ad >> 8) & 3) << 4;
            afr[mf] = *(const s16x8*)((const char*)As + ad);
        }
        #pragma unroll
        for (int nf = 0; nf < 2; ++nf) {
            int ad = (wc * 32 + nf * 16 + i16) * 64 + quad * 16;
            ad ^= ((ad >> 8) & 3) << 4;
            bfr[nf] = *(const s16x8*)((const char*)Bs + ad);
        }
        if (kt < 29) OSTAGE(kt + 3);
        #pragma unroll
        for (int mf = 0; mf < 4; ++mf)
            #pragma unroll
            for (int nf = 0; nf < 2; ++nf)
                acc[mf][nf] = __builtin_amdgcn_mfma_f32_16x16x32_bf16(
                    afr[mf], bfr[nf], acc[mf][nf], 0, 0, 0);

        if (kt <= 28)      { asm volatile("s_waitcnt vmcnt(4)" ::: "memory"); }
        else if (kt == 29) { asm volatile("s_waitcnt vmcnt(2)" ::: "memory"); }
        else if (kt == 30) { asm volatile("s_waitcnt vmcnt(0)" ::: "memory"); }
        __builtin_amdgcn_s_barrier();
        __builtin_amdgcn_sched_barrier(0);
    }
#undef OSTAGE

    #pragma unroll
    for (int mf = 0; mf < 4; ++mf)
        #pragma unroll
        for (int nf = 0; nf < 2; ++nf) {
            const int od = n0 + wc * 32 + nf * 16 + i16;
            const int tk = m0 + wr * 64 + mf * 16 + quad * 4;
            #pragma unroll
            for (int r = 0; r < 4; ++r)
                out[(size_t)(tk + r) * D + od] = acc[mf][nf][r];
        }
}

// ---------------------------------------------------------------------------
// MFMA flash attention v5: 8 waves x 16 q-rows, 512 threads, grid 16x32,
// qt-pairing load balance, linear [64][64] K/V LDS + both-sides XOR swizzle,
// gl_lds staging depth-2 ring. Verified round 6. Unchanged.
// ---------------------------------------------------------------------------
__global__ __launch_bounds__(512)
void attn_mfma(const ushort* __restrict__ Q, const ushort* __restrict__ K,
               const ushort* __restrict__ Vt, ushort* __restrict__ Yb)
{
    const int bh   = blockIdx.y;
    const int qt   = (bh < 16) ? (15 - blockIdx.x) : blockIdx.x;
    const int tid  = threadIdx.x;
    const int wave = tid >> 6, lane = tid & 63;
    const int i16  = lane & 15, quad = lane >> 4;
    const int r0   = qt * 128 + wave * 16;
    const int row  = r0 + i16;
    const int jtmax = (r0 + 15) >> 6;        // this wave's diagonal k-tile
    const int jtend = 2 * qt + 1;            // block's last k-tile

    __shared__ __align__(16) ushort Ks[2][64 * 64];
    __shared__ __align__(16) ushort Vs[2][64 * 64];
    __shared__ __align__(16) ushort Ps[8][16 * 72];

    const ushort* Qb = Q  + (size_t)bh * L * KS;
    const ushort* Kb = K  + (size_t)bh * L * KS;
    const ushort* Vb = Vt + (size_t)bh * KS * L;

    const s16x8 qf0 = *(const s16x8*)(Qb + (size_t)row * KS + quad * 8);
    const s16x8 qf1 = *(const s16x8*)(Qb + (size_t)row * KS + 32 + quad * 8);

    const int srow = tid >> 3;                               // 0..63
    const int scol = ((tid & 7) ^ ((tid >> 3) & 7)) * 8;     // ushorts
    ushort* kd0 = &Ks[0][0] + tid * 8;
    ushort* vd0 = &Vs[0][0] + tid * 8;
    ushort* kd1 = &Ks[1][0] + tid * 8;
    ushort* vd1 = &Vs[1][0] + tid * 8;

    gl_lds16(Kb + (size_t)srow * KS + scol, kd0);
    gl_lds16(Vb + (size_t)srow * L + scol, vd0);
    asm volatile("s_waitcnt vmcnt(0)" ::: "memory");
    __builtin_amdgcn_s_barrier();

    f32x4 O0 = {0.f,0.f,0.f,0.f}, O1 = O0, O2 = O0, O3 = O0;
    float psum = 0.0f;
    const int xk = (i16 & 7) << 4;           // read swizzle key (row = nt*16+i16)

    #pragma unroll 1
    for (int jt = 0; jt <= jtend; ++jt) {
        const int cur = jt & 1;
        const bool has_next = (jt < jtend);

        if (has_next) {
            const int j0n = (jt + 1) * 64;
            gl_lds16(Kb + (size_t)(j0n + srow) * KS + scol, cur ? kd0 : kd1);
            gl_lds16(Vb + (size_t)srow * L + j0n + scol,    cur ? vd0 : vd1);
        }

        if (jt <= jtmax) {
            const int j0 = jt * 64;
            const char* Ksb = (const char*)&Ks[cur][0];
            const char* Vsb = (const char*)&Vs[cur][0];
            f32x4 st[4];
            #pragma unroll
            for (int nt = 0; nt < 4; ++nt) {
                const int rb = (nt * 16 + i16) * 128 + quad * 16;
                const s16x8 kf0 = *(const s16x8*)(Ksb + (rb ^ xk));
                const s16x8 kf1 = *(const s16x8*)(Ksb + ((rb + 64) ^ xk));
                f32x4 c = {0.f,0.f,0.f,0.f};
                c = __builtin_amdgcn_mfma_f32_16x16x32_bf16(kf0, qf0, c, 0, 0, 0);
                c = __builtin_amdgcn_mfma_f32_16x16x32_bf16(kf1, qf1, c, 0, 0, 0);
                st[nt] = c;
            }
            if (jt == jtmax) {
                #pragma unroll
                for (int nt = 0; nt < 4; ++nt)
                    #pragma unroll
                    for (int rg = 0; rg < 4; ++rg) {
                        const int j = j0 + nt * 16 + quad * 4 + rg;
                        if (j > row) st[nt][rg] = -1e30f;
                    }
            }
            float pv[4][4];
            #pragma unroll
            for (int nt = 0; nt < 4; ++nt)
                #pragma unroll
                for (int rg = 0; rg < 4; ++rg) {
                    pv[nt][rg] = __expf(st[nt][rg]);
                    psum += pv[nt][rg];
                }
            ushort* P2 = &Ps[wave][0];
            #pragma unroll
            for (int nt = 0; nt < 4; ++nt) {
                uint2 pk;
                pk.x = __builtin_amdgcn_perm(fbits(pv[nt][1]), fbits(pv[nt][0]), 0x07060302u);
                pk.y = __builtin_amdgcn_perm(fbits(pv[nt][3]), fbits(pv[nt][2]), 0x07060302u);
                *(uint2*)(P2 + i16 * 72 + nt * 16 + quad * 4) = pk;
            }
            const s16x8 pf0 = *(const s16x8*)(P2 + i16 * 72 + quad * 8);
            const s16x8 pf1 = *(const s16x8*)(P2 + i16 * 72 + 32 + quad * 8);
            s16x8 v0, v1;
            int vb0 = (0 * 16 + i16) * 128 + quad * 16;
            v0 = *(const s16x8*)(Vsb + (vb0 ^ xk));
            v1 = *(const s16x8*)(Vsb + ((vb0 + 64) ^ xk));
            O0 = __builtin_amdgcn_mfma_f32_16x16x32_bf16(v0, pf0, O0, 0, 0, 0);
            O0 = __builtin_amdgcn_mfma_f32_16x16x32_bf16(v1, pf1, O0, 0, 0, 0);
            vb0 = (1 * 16 + i16) * 128 + quad * 16;
            v0 = *(const s16x8*)(Vsb + (vb0 ^ xk));
            v1 = *(const s16x8*)(Vsb + ((vb0 + 64) ^ xk));
            O1 = __builtin_amdgcn_mfma_f32_16x16x32_bf16(v0, pf0, O1, 0, 0, 0);
            O1 = __builtin_amdgcn_mfma_f32_16x16x32_bf16(v1, pf1, O1, 0, 0, 0);
            vb0 = (2 * 16 + i16) * 128 + quad * 16;
            v0 = *(const s16x8*)(Vsb + (vb0 ^ xk));
            v1 = *(const s16x8*)(Vsb + ((vb0 + 64) ^ xk));
            O2 = __builtin_amdgcn_mfma_f32_16x16x32_bf16(v0, pf0, O2, 0, 0, 0);
            O2 = __builtin_amdgcn_mfma_f32_16x16x32_bf16(v1, pf1, O2, 0, 0, 0);
            vb0 = (3 * 16 + i16) * 128 + quad * 16;
            v0 = *(const s16x8*)(Vsb + (vb0 ^ xk));
            v1 = *(const s16x8*)(Vsb + ((vb0 + 64) ^ xk));
            O3 = __builtin_amdgcn_mfma_f32_16x16x32_bf16(v0, pf0, O3, 0, 0, 0);
            O3 = __builtin_amdgcn_mfma_f32_16x16x32_bf16(v1, pf1, O3, 0, 0, 0);
        }

        if (has_next) {
            asm volatile("s_waitcnt vmcnt(0)" ::: "memory");
            __builtin_amdgcn_s_barrier();
        }
    }

    psum += __shfl_xor(psum, 16);
    psum += __shfl_xor(psum, 32);
    const float inv_l = __builtin_amdgcn_rcpf(psum);
    const int b = bh >> 4, hh = bh & 15;
    ushort* Yp = Yb + ((size_t)(b * L + row)) * D + hh * KS + quad * 4;
    f32x4 r;
    r = O0 * inv_l; *(ushort4*)(Yp +  0) = make_ushort4(f2bf(r[0]),f2bf(r[1]),f2bf(r[2]),f2bf(r[3]));
    r = O1 * inv_l; *(ushort4*)(Yp + 16) = make_ushort4(f2bf(r[0]),f2bf(r[1]),f2bf(r[2]),f2bf(r[3]));
    r = O2 * inv_l; *(ushort4*)(Yp + 32) = make_ushort4(f2bf(r[0]),f2bf(r[1]),f2bf(r[2]),f2bf(r[3]));
    r = O3 * inv_l; *(ushort4*)(Yp + 48) = make_ushort4(f2bf(r[0]),f2bf(r[1]),f2bf(r[2]),f2bf(r[3]));
}

// ---------------------------------------------------------------------------
extern "C" void kernel_launch(void* const* d_in, const int* in_sizes, int n_in,
                              void* d_out, int out_size, void* d_ws, size_t ws_size,
                              hipStream_t stream)
{
    const float* x  = (const float*)d_in[0];
    // d_in[1] = mask (unused; causal handled analytically)
    const float* Wq = (const float*)d_in[2];
    const float* Wk = (const float*)d_in[3];
    const float* Wv = (const float*)d_in[4];
    const float* Wo = (const float*)d_in[5];

    const size_t NTOK = (size_t)BBATCH * L;         // 4096
    const size_t SZ   = NTOK * D;                   // 4 M elems
    ushort* xb  = (ushort*)d_ws;                    // [4096][1024]
    ushort* Wt  = xb + SZ;                          // [Wq^T;Wk^T;Wv^T;Wo^T]
    ushort* Qb  = Wt + 4 * (size_t)D * D;           // [bh][l][64]
    ushort* Kb  = Qb + SZ;
    ushort* Vtb = Kb + SZ;                          // [bh][64][l]
    ushort* Yb  = Vtb + SZ;                         // [4096][1024]
    float2* tab = (float2*)Yb;                      // aliases Yb: consumed by
                                                    // qkv before attn writes Yb

    prep<<<dim3(8448), dim3(256), 0, stream>>>(x, Wq, Wk, Wv, Wo, xb, Wt, tab);

    qkv_gemm<<<dim3(16, 16), dim3(512), 0, stream>>>(Wt, xb, tab, Qb, Kb, Vtb);

    attn_mfma<<<dim3(16, 32), dim3(512), 0, stream>>>(Qb, Kb, Vtb, Yb);

    oproj_gemm<<<dim3(8, 32), dim3(512), 0, stream>>>(Yb, Wt + 3 * (size_t)D * D,
                                                      (float*)d_out);
}